// Round 5
// baseline (396.240 us; speedup 1.0000x reference)
//
#include <hip/hip_runtime.h>
#include <hip/hip_bf16.h>
#include <math.h>

typedef __bf16 bf16;
typedef __attribute__((ext_vector_type(8))) __bf16 bf16x8;
typedef __attribute__((ext_vector_type(4))) __bf16 bf16x4;
typedef __attribute__((ext_vector_type(4))) float f32x4;
typedef __attribute__((ext_vector_type(16))) float f32x16;

constexpr int BM = 256, BN = 128, BK = 32;

enum { EPI_PLAIN = 0, EPI_GELU = 1, EPI_RES = 2, EPI_GATE = 3 };

__device__ __forceinline__ void async16(const void* g, void* l) {
  __builtin_amdgcn_global_load_lds(
      (const __attribute__((address_space(1))) void*)g,
      (__attribute__((address_space(3))) void*)l, 16, 0, 0);
}

// barrier draining LDS ops but NOT the global_load_lds queue (vmcnt counted).
__device__ __forceinline__ void bar_lgkm() {
  asm volatile("s_waitcnt lgkmcnt(0)\n\ts_barrier" ::: "memory");
}

#define WAIT_VM(n) asm volatile("s_waitcnt vmcnt(" #n ")" ::: "memory")

// ---------------------------------------------------------------------------
// bf16 GEMM, C = A[M,K] @ B[N,K]^T + epilogue.
// Round-5: 32x32x16 MFMA with square 64x64 wave tiles -- doubles FLOP per
// LDS byte (32.8 vs 21.8 F/B), halving the LDS-read pipe that round-4
// accounting showed as the largest consumer (~48% of cycles), and halves
// MFMA instruction count (8-cyc 32x32x16 vs 4.8-cyc 16x16x32).
//   - block 256x128, 8 waves in 4x2 grid; BK=32 (two k=16 subs).
//   - LDS layout UNCHANGED ([rows][32k], 64B rows) and the HW-verified XOR
//     involution slot^=(row>>1)&3 stays conflict-free for the 32-row
//     operand pattern: each 8-consecutive-lane group spans 8 consecutive
//     rows -> 8 distinct (row-parity, slot) classes = all 32 banks.
//   - dbuf 48KB (A 16KB + B 8KB per buf), counted WAIT_VM(3), 2 barriers
//     per K-step, XCD-chunked block remap (bn-fastest) -- all carried over.
// C/D layout (m74/m101): col = lane&31, row = (reg&3)+8*(reg>>2)+4*(lane>>5).
// ---------------------------------------------------------------------------
template <typename CT, int EPI>
__global__ __launch_bounds__(512, 4) void gemm_bt_a(
    const bf16* __restrict__ A, const bf16* __restrict__ B, CT* __restrict__ C,
    const float* __restrict__ bias, const bf16* __restrict__ resid,
    const float* __restrict__ sup, const float* __restrict__ wsg,
    const float* __restrict__ bsg, int M, int N, int K) {
  __shared__ bf16 As[2][BM * BK];  // 16 KB per buf
  __shared__ bf16 Bs[2][BN * BK];  // 8 KB per buf

  const int tid = threadIdx.x;
  // XCD-chunked remap (bijective; nwg % 8 == 0 for all grids used here).
  const int nwg = gridDim.x;
  const int cpx = nwg >> 3;
  const int wg = blockIdx.x;
  const int sw = (wg & 7) * cpx + (wg >> 3);
  const int ntn = N >> 7;  // N / BN
  const int bm = sw / ntn, bn = sw - bm * ntn;

  const int lane = tid & 63;
  const int wv = tid >> 6;
  const int wm = (wv >> 1) * 64, wn = (wv & 1) * 64;  // 4x2 wave grid
  const int l32 = lane & 31, kh = lane >> 5;

  f32x16 acc[2][2];
#pragma unroll
  for (int i = 0; i < 2; i++)
#pragma unroll
    for (int j = 0; j < 2; j++)
#pragma unroll
      for (int r = 0; r < 16; r++) acc[i][j][r] = 0.f;

  // ---- staging (linear LDS dest; source slot pre-swizzled) ----
  const int srow = tid >> 2;
  const int sq8 = ((tid & 3) ^ ((srow >> 1) & 3)) * 8;  // +128 rows: class unchanged
  const bf16* pa0 = A + (size_t)(bm * BM + srow) * K + sq8;
  const bf16* pa1 = pa0 + (size_t)128 * K;
  const bf16* pb = B + (size_t)(bn * BN + srow) * K + sq8;
  bf16* dA = &As[0][0] + wv * 512;  // wave-uniform base; HW adds lane*16B
  bf16* dB = &Bs[0][0] + wv * 512;

  auto stg = [&](int buf) {
    bf16* a = dA + buf * (BM * BK);
    async16(pa0, a);           // rows 0..127
    async16(pa1, a + 4096);    // rows 128..255
    async16(pb, dB + buf * (BN * BK));
    pa0 += BK;
    pa1 += BK;
    pb += BK;
  };

  // ---- read-side offsets (swizzled slot within 64B row) ----
  int rA[2], swA[2], rB[2], swB[2];
#pragma unroll
  for (int mi = 0; mi < 2; mi++) {
    int row = wm + mi * 32 + l32;
    rA[mi] = row * BK;
    swA[mi] = (row >> 1) & 3;
  }
#pragma unroll
  for (int ni = 0; ni < 2; ni++) {
    int col = wn + ni * 32 + l32;
    rB[ni] = col * BK;
    swB[ni] = (col >> 1) & 3;
  }

  stg(0);  // prologue: tile 0 in flight (3 loads/thread)

  const int nt = K / BK;
  for (int t = 0; t < nt; ++t) {
    const int cur = t & 1;
    if (t + 1 < nt) {
      stg(cur ^ 1);  // issue next tile first
      WAIT_VM(3);    // tile t landed; tile t+1's 3 loads stay in flight
    } else {
      WAIT_VM(0);
    }
    bar_lgkm();

    bf16x8 a[2][2], b[2][2];  // [ksub][frag]
#pragma unroll
    for (int kk = 0; kk < 2; kk++) {
      const int s = (kk << 1) | kh;
#pragma unroll
      for (int mi = 0; mi < 2; mi++)
        a[kk][mi] = *(const bf16x8*)&As[cur][rA[mi] + ((s ^ swA[mi]) << 3)];
#pragma unroll
      for (int ni = 0; ni < 2; ni++)
        b[kk][ni] = *(const bf16x8*)&Bs[cur][rB[ni] + ((s ^ swB[ni]) << 3)];
    }
#pragma unroll
    for (int kk = 0; kk < 2; kk++)
#pragma unroll
      for (int mi = 0; mi < 2; mi++)
#pragma unroll
        for (int ni = 0; ni < 2; ni++)
          acc[mi][ni] = __builtin_amdgcn_mfma_f32_32x32x16_bf16(
              a[kk][mi], b[kk][ni], acc[mi][ni], 0, 0, 0);
    bar_lgkm();  // all waves done reading buf[cur] before next stg overwrites
  }

  // ---- epilogue: col = l32, row = rbase + (reg&3) + 8*(reg>>2) ----
#pragma unroll
  for (int mi = 0; mi < 2; mi++) {
    const int rbase = bm * BM + wm + mi * 32 + 4 * kh;
#pragma unroll
    for (int ni = 0; ni < 2; ni++) {
      const int col = bn * BN + wn + ni * 32 + l32;
#pragma unroll
      for (int r = 0; r < 16; r++) {
        const int row = rbase + (r & 3) + 8 * (r >> 2);
        const size_t idx = (size_t)row * N + col;
        float v = acc[mi][ni][r];
        if constexpr (EPI == EPI_PLAIN) {
          C[idx] = (CT)v;
        } else if constexpr (EPI == EPI_GELU) {
          v += bias[col];
          float gl = 0.5f * v * (1.0f + erff(v * 0.70710678118654752f));
          C[idx] = (CT)gl;
        } else if constexpr (EPI == EPI_RES) {
          v += bias[col] + (float)resid[idx];
          C[idx] = (CT)v;
        } else {  // EPI_GATE
          v += bias[col];
          float g1 = 1.0f / (1.0f + expf(-v));
          float z = sup[row] * wsg[col] + bsg[col];
          float g2 = 1.0f / (1.0f + expf(-z));
          C[idx] = (CT)(g1 * g2);
        }
      }
    }
  }
}

// ---------------- chunked parallel scan ----------------
constexpr int SC_CH = 32, SC_NCH = 16, SC_CW = 32;

__global__ __launch_bounds__(512) void scan2_kernel(const float* __restrict__ g,
                                                    const bf16* __restrict__ xt,
                                                    bf16* __restrict__ s, int T, int C) {
  __shared__ float lA[SC_NCH][SC_CW];
  __shared__ float lB[SC_NCH][SC_CW];
  __shared__ float lC[SC_NCH][SC_CW];
  const int cl = threadIdx.x & (SC_CW - 1);
  const int ch = threadIdx.x / SC_CW;
  const int c = blockIdx.x * SC_CW + cl;
  const int n = blockIdx.y;
  const size_t base = ((size_t)n * T + ch * SC_CH) * C + c;

  float a_arr[SC_CH], sl[SC_CH];
  float A = 1.f, B = 0.f;
#pragma unroll
  for (int t = 0; t < SC_CH; ++t) {
    size_t idx = base + (size_t)t * C;
    float gv = g[idx], xv = (float)xt[idx];
    float at = 1.0f - gv;
    a_arr[t] = at;
    B = at * B + gv * xv;
    sl[t] = B;
    A *= at;
  }
  lA[ch][cl] = A;
  lB[ch][cl] = B;
  __syncthreads();
  if (ch == 0) {
    float carry = 0.f;
#pragma unroll
    for (int j = 0; j < SC_NCH; ++j) {
      lC[j][cl] = carry;
      carry = lA[j][cl] * carry + lB[j][cl];
    }
  }
  __syncthreads();
  const float carry = lC[ch][cl];
  float P = 1.f;
#pragma unroll
  for (int t = 0; t < SC_CH; ++t) {
    P *= a_arr[t];
    s[base + (size_t)t * C] = (bf16)(sl[t] + P * carry);
  }
}

// ---------------- weight converts (fused 5-way, scalar) ----------------
__global__ __launch_bounds__(256) void cvt5_kernel(
    const float* s0, bf16* d0, int n0, const float* s1, bf16* d1, int n1,
    const float* s2, bf16* d2, int n2, const float* s3, bf16* d3, int n3,
    const float* s4, bf16* d4, int n4) {
  const float* s; bf16* d; int n;
  switch (blockIdx.y) {
    case 0: s = s0; d = d0; n = n0; break;
    case 1: s = s1; d = d1; n = n1; break;
    case 2: s = s2; d = d2; n = n2; break;
    case 3: s = s3; d = d3; n = n3; break;
    default: s = s4; d = d4; n = n4; break;
  }
  int i = blockIdx.x * 256 + threadIdx.x;
  if (i < n) d[i] = (bf16)s[i];
}

// ---------------- vectorized fp32 -> bf16 (x_seq), n % 4 == 0 ----------------
__global__ __launch_bounds__(256) void cvtx_kernel(const float* __restrict__ in,
                                                   bf16* __restrict__ out, int n4) {
  int i = blockIdx.x * 256 + threadIdx.x;
  if (i < n4) {
    f32x4 v = *(const f32x4*)(in + (size_t)i * 4);
    bf16x4 b;
    b[0] = (bf16)v[0]; b[1] = (bf16)v[1]; b[2] = (bf16)v[2]; b[3] = (bf16)v[3];
    *(bf16x4*)(out + (size_t)i * 4) = b;
  }
}

extern "C" void kernel_launch(void* const* d_in, const int* in_sizes, int n_in,
                              void* d_out, int out_size, void* d_ws, size_t ws_size,
                              hipStream_t stream) {
  const float* x_seq = (const float*)d_in[0];
  const float* sup = (const float*)d_in[1];
  const float* W_in = (const float*)d_in[2];
  const float* W_out = (const float*)d_in[3];
  const float* W_bg = (const float*)d_in[4];
  const float* b_bg = (const float*)d_in[5];
  const float* W_sg = (const float*)d_in[6];
  const float* b_sg = (const float*)d_in[7];
  const float* W_f1 = (const float*)d_in[8];
  const float* b_f1 = (const float*)d_in[9];
  const float* W_f2 = (const float*)d_in[10];
  const float* b_f2 = (const float*)d_in[11];

  const int Nb = 32, T = 512, C = 768, H = 1536;
  const int M = Nb * T;  // 16384

  char* ws = (char*)d_ws;
  size_t off = 0;
  auto alloc = [&](size_t bytes) {
    void* p = ws + off;
    off += (bytes + 255) & ~(size_t)255;
    return p;
  };
  bf16* Win_bf = (bf16*)alloc((size_t)C * C * 2);
  bf16* Wf1_bf = (bf16*)alloc((size_t)H * C * 2);
  bf16* Wf2_bf = (bf16*)alloc((size_t)C * H * 2);
  bf16* Wbg_bf = (bf16*)alloc((size_t)C * C * 2);
  bf16* Wout_bf = (bf16*)alloc((size_t)C * C * 2);
  bf16* xs_bf = (bf16*)alloc((size_t)M * C * 2);  // x_seq bf16
  bf16* x_bf = (bf16*)alloc((size_t)M * C * 2);   // x; reused as s after G3
  bf16* h_bf = (bf16*)alloc((size_t)M * H * 2);
  bf16* xt_bf = (bf16*)alloc((size_t)M * C * 2);
  float* g_f = (float*)alloc((size_t)M * C * 4);
  bf16* s_bf = x_bf;  // x dead after G3

  cvt5_kernel<<<dim3((H * C + 255) / 256, 5), 256, 0, stream>>>(
      W_in, Win_bf, C * C, W_f1, Wf1_bf, H * C, W_f2, Wf2_bf, C * H,
      W_bg, Wbg_bf, C * C, W_out, Wout_bf, C * C);
  cvtx_kernel<<<(M * C / 4 + 255) / 256, 256, 0, stream>>>(x_seq, xs_bf, M * C / 4);

  dim3 blk(512);
  // 1D grids (XCD remap in-kernel); nwg % 8 == 0 for all of these.
  // G1: x = x_seq @ W_in^T
  gemm_bt_a<bf16, EPI_PLAIN><<<dim3((M / BM) * (C / BN)), blk, 0, stream>>>(
      xs_bf, Win_bf, x_bf, nullptr, nullptr, nullptr, nullptr, nullptr, M, C, C);
  // G2: h = gelu(x @ W_f1^T + b_f1)
  gemm_bt_a<bf16, EPI_GELU><<<dim3((M / BM) * (H / BN)), blk, 0, stream>>>(
      x_bf, Wf1_bf, h_bf, b_f1, nullptr, nullptr, nullptr, nullptr, M, H, C);
  // G3: xt = x + h @ W_f2^T + b_f2
  gemm_bt_a<bf16, EPI_RES><<<dim3((M / BM) * (C / BN)), blk, 0, stream>>>(
      h_bf, Wf2_bf, xt_bf, b_f2, x_bf, nullptr, nullptr, nullptr, M, C, H);
  // G4: g = sigmoid(xt @ W_bg^T + b_bg) * sigmoid(sup*W_sg + b_sg)  (fp32 out)
  gemm_bt_a<float, EPI_GATE><<<dim3((M / BM) * (C / BN)), blk, 0, stream>>>(
      xt_bf, Wbg_bf, g_f, b_bg, nullptr, sup, W_sg, b_sg, M, C, C);
  // scan
  scan2_kernel<<<dim3(C / SC_CW, Nb), dim3(SC_CW * SC_NCH), 0, stream>>>(
      g_f, xt_bf, s_bf, T, C);
  // G6: out = s @ W_out^T (fp32 out)
  gemm_bt_a<float, EPI_PLAIN><<<dim3((M / BM) * (C / BN)), blk, 0, stream>>>(
      s_bf, Wout_bf, (float*)d_out, nullptr, nullptr, nullptr, nullptr, nullptr, M, C, C);
}